// Round 2
// baseline (408.391 us; speedup 1.0000x reference)
//
#include <hip/hip_runtime.h>
#include <math.h>

#define BATCH_N 16384

// ---------------------------------------------------------------------------
// K12: fused conv1(1->6,5x5)+relu+pool + conv2(6->16,5x5)+relu+pool
//      x: (B,1,28,28) -> h2: (B,256)   [h1 never touches HBM]
// Block = 2 samples, 128 threads.
// Phase 1: task = pooled conv1 output (144/sample, 288 tasks): 6x6 patch in
//   registers, 6 oc x 4 conv positions accumulated with WAVE-UNIFORM scalar
//   weights (s_load, no LDS/VALU cost). h1 -> LDS.
// Phase 2: thread = conv2 position (64/sample): 5x5 patch per ic, 16 oc
//   accumulators, scalar weights. Pool via shfl_xor(1)/shfl_xor(8),
//   coalesced float4 store through LDS staging.
// ---------------------------------------------------------------------------
__global__ __launch_bounds__(128) void k12_conv(const float* __restrict__ x,
                                                const float* __restrict__ w1,
                                                const float* __restrict__ b1,
                                                const float* __restrict__ w2,
                                                const float* __restrict__ b2,
                                                float* __restrict__ h2out) {
    __shared__ float xs[2 * 784];   // 2 samples of 28x28 input (reused as h2 staging)
    __shared__ float hs[2 * 864];   // 2 samples of h1 (6,12,12)
    const int tid = threadIdx.x;
    const int b0 = blockIdx.x * 2;

    // ---- load x (2 x 196 float4, coalesced) ----
    for (int i = tid; i < 392; i += 128)
        ((float4*)xs)[i] = ((const float4*)(x + (size_t)b0 * 784))[i];
    __syncthreads();

    // ---- phase 1: conv1 + relu + pool -> hs ----
    for (int task = tid; task < 288; task += 128) {
        const int s = (task >= 144) ? 1 : 0;
        const int r = task - s * 144;
        const int py = r / 12, px = r - (r / 12) * 12;
        const float* xp = xs + s * 784 + (2 * py) * 28 + 2 * px;
        float p[6][6];
#pragma unroll
        for (int rr = 0; rr < 6; rr++) {
            float2 u = *(const float2*)(xp + rr * 28);
            float2 v = *(const float2*)(xp + rr * 28 + 2);
            float2 t = *(const float2*)(xp + rr * 28 + 4);
            p[rr][0] = u.x; p[rr][1] = u.y; p[rr][2] = v.x;
            p[rr][3] = v.y; p[rr][4] = t.x; p[rr][5] = t.y;
        }
#pragma unroll
        for (int oc = 0; oc < 6; oc++) {
            const float bv = b1[oc];
            float a00 = bv, a01 = bv, a10 = bv, a11 = bv;
#pragma unroll
            for (int ky = 0; ky < 5; ky++)
#pragma unroll
                for (int kx = 0; kx < 5; kx++) {
                    const float wv = w1[oc * 25 + ky * 5 + kx];  // wave-uniform -> s_load
                    a00 = fmaf(wv, p[ky][kx],         a00);
                    a01 = fmaf(wv, p[ky][kx + 1],     a01);
                    a10 = fmaf(wv, p[ky + 1][kx],     a10);
                    a11 = fmaf(wv, p[ky + 1][kx + 1], a11);
                }
            const float m = fmaxf(fmaxf(a00, a01), fmaxf(a10, a11));
            hs[s * 864 + oc * 144 + py * 12 + px] = fmaxf(m, 0.f);
        }
    }
    __syncthreads();

    // ---- phase 2: conv2 + relu + pool ----
    const int s = tid >> 6;          // wave 0 = sample 0, wave 1 = sample 1
    const int pp = tid & 63;         // conv position 0..63
    const int cy = pp >> 3, cx = pp & 7;

    float acc[16];
#pragma unroll
    for (int oc = 0; oc < 16; oc++) acc[oc] = b2[oc];

    for (int ic = 0; ic < 6; ic++) {
        const float* xp = hs + s * 864 + ic * 144 + cy * 12 + cx;
        float p5[25];
#pragma unroll
        for (int rr = 0; rr < 5; rr++)
#pragma unroll
            for (int cc = 0; cc < 5; cc++) p5[rr * 5 + cc] = xp[rr * 12 + cc];
#pragma unroll
        for (int oc = 0; oc < 16; oc++) {
            float a = acc[oc];
#pragma unroll
            for (int k = 0; k < 25; k++)
                a = fmaf(w2[(oc * 6 + ic) * 25 + k], p5[k], a);  // wave-uniform -> s_load
            acc[oc] = a;
        }
    }

    // pool over (cy,cx) pairs: partners are lane^1 (x) and lane^8 (y)
    float* stage = xs;  // reuse xs as h2 staging: [2][256]
#pragma unroll
    for (int oc = 0; oc < 16; oc++) {
        float v = acc[oc];
        v = fmaxf(v, __shfl_xor(v, 1));
        v = fmaxf(v, __shfl_xor(v, 8));
        if ((pp & 9) == 0)
            stage[s * 256 + oc * 16 + (cy >> 1) * 4 + (cx >> 1)] = fmaxf(v, 0.f);
    }
    __syncthreads();

    // coalesced h2 write: 2*64 float4 by 128 threads
    ((float4*)(h2out + (size_t)b0 * 256))[tid] = ((const float4*)stage)[tid];
}

// ---------------------------------------------------------------------------
// K3: fc1 (256->120) + bias + relu, then fc2 (120->4) + bias + pi*sigmoid
//     h2: (B,256) -> angles: (B,4)
// ---------------------------------------------------------------------------
__global__ __launch_bounds__(256) void k3_fc(const float* __restrict__ h2,
                                             const float* __restrict__ w1,
                                             const float* __restrict__ b1,
                                             const float* __restrict__ w2,
                                             const float* __restrict__ b2,
                                             float* __restrict__ angles) {
    __shared__ float As[64 * 17];
    __shared__ float Bs[128 * 17];
    __shared__ float Hs[64 * 121];
    const int tid = threadIdx.x;
    const int s0 = blockIdx.x * 64;
    const int tx = tid & 15, ty = tid >> 4;

    float acc[4][8];
#pragma unroll
    for (int i = 0; i < 4; i++)
#pragma unroll
        for (int j = 0; j < 8; j++) acc[i][j] = 0.f;

    for (int k0 = 0; k0 < 256; k0 += 16) {
#pragma unroll
        for (int i = 0; i < 4; i++)
            As[(ty + 16 * i) * 17 + tx] = h2[(size_t)(s0 + ty + 16 * i) * 256 + k0 + tx];
#pragma unroll
        for (int j = 0; j < 8; j++) {
            const int n = ty + 16 * j;
            Bs[n * 17 + tx] = (n < 120) ? w1[(size_t)n * 256 + k0 + tx] : 0.f;
        }
        __syncthreads();
#pragma unroll
        for (int kk = 0; kk < 16; kk++) {
            float av[4], bv[8];
#pragma unroll
            for (int i = 0; i < 4; i++) av[i] = As[(ty + 16 * i) * 17 + kk];
#pragma unroll
            for (int j = 0; j < 8; j++) bv[j] = Bs[(tx + 16 * j) * 17 + kk];
#pragma unroll
            for (int i = 0; i < 4; i++)
#pragma unroll
                for (int j = 0; j < 8; j++) acc[i][j] = fmaf(av[i], bv[j], acc[i][j]);
        }
        __syncthreads();
    }

#pragma unroll
    for (int j = 0; j < 8; j++) {
        const int n = tx + 16 * j;
        if (n < 120) {
            const float bv = b1[n];
#pragma unroll
            for (int i = 0; i < 4; i++)
                Hs[(ty + 16 * i) * 121 + n] = fmaxf(acc[i][j] + bv, 0.f);
        }
    }
    __syncthreads();

    const int s = tid >> 2, m = tid & 3;
    float f = b2[m];
    for (int n = 0; n < 120; n++) f = fmaf(w2[m * 120 + n], Hs[s * 121 + n], f);
    const float ang = 3.14159265358979323846f / (1.f + expf(-f));
    angles[(size_t)(s0 + s) * 4 + m] = ang;
}

// ---------------------------------------------------------------------------
// K4: 4-qubit, 3-layer circuit + classifier (4->10). One thread per sample.
// ---------------------------------------------------------------------------
__global__ __launch_bounds__(256) void k4_circuit(const float* __restrict__ angles,
                                                  const float* __restrict__ qw,
                                                  const float* __restrict__ cw,
                                                  const float* __restrict__ cb,
                                                  float* __restrict__ out) {
    const int b = blockIdx.x * 256 + threadIdx.x;
    const float4 a4 = ((const float4*)angles)[b];
    const float av[4] = {a4.x, a4.y, a4.z, a4.w};

    float sr[16], si[16];
#pragma unroll
    for (int i = 0; i < 16; i++) { sr[i] = 0.f; si[i] = 0.f; }
    sr[0] = 1.f;

#pragma unroll
    for (int l = 0; l < 3; l++) {
#pragma unroll
        for (int w = 0; w < 4; w++) {
            const float phi = qw[(l * 4 + w) * 3 + 0];
            const float th  = qw[(l * 4 + w) * 3 + 1];
            const float om  = qw[(l * 4 + w) * 3 + 2];
            const float ct = cosf(0.5f * th), st = sinf(0.5f * th);
            const float ap = 0.5f * (phi + om), bm = 0.5f * (phi - om);
            const float ca = cosf(ap), sa = sinf(ap);
            const float cbm = cosf(bm), sbm = sinf(bm);
            const float m00r =  ct * ca,  m00i = -ct * sa;
            const float m01r = -st * cbm, m01i = -st * sbm;
            const float m10r =  st * cbm, m10i = -st * sbm;
            const float m11r =  ct * ca,  m11i =  ct * sa;
            const int mask = 8 >> w;
#pragma unroll
            for (int i = 0; i < 16; i++)
                if (!(i & mask)) {
                    const int j = i | mask;
                    const float xr = sr[i], xi = si[i], yr = sr[j], yi = si[j];
                    sr[i] = m00r * xr - m00i * xi + m01r * yr - m01i * yi;
                    si[i] = m00r * xi + m00i * xr + m01r * yi + m01i * yr;
                    sr[j] = m10r * xr - m10i * xi + m11r * yr - m11i * yi;
                    si[j] = m10r * xi + m10i * xr + m11r * yi + m11i * yr;
                }
        }
#pragma unroll
        for (int w = 0; w < 4; w++) {
            const int mc = 8 >> w, mt = 8 >> ((w + 1) & 3);
#pragma unroll
            for (int i = 0; i < 16; i++)
                if ((i & mc) && !(i & mt)) {
                    const int j = i | mt;
                    const float tr = sr[i], ti = si[i];
                    sr[i] = sr[j]; si[i] = si[j];
                    sr[j] = tr;    si[j] = ti;
                }
        }
#pragma unroll
        for (int w = 0; w < 4; w++) {
            const float c = cosf(0.5f * av[w]), s = sinf(0.5f * av[w]);
            const int mask = 8 >> w;
#pragma unroll
            for (int i = 0; i < 16; i++)
                if (!(i & mask)) {
                    const int j = i | mask;
                    const float xr = sr[i], xi = si[i], yr = sr[j], yi = si[j];
                    sr[i] = c * xr + s * yi;
                    si[i] = c * xi - s * yr;
                    sr[j] = c * yr + s * xi;
                    si[j] = c * yi - s * xr;
                }
        }
    }

    float z[4];
#pragma unroll
    for (int w = 0; w < 4; w++) {
        const int mask = 8 >> w;
        float zacc = 0.f;
#pragma unroll
        for (int i = 0; i < 16; i++) {
            const float pv = sr[i] * sr[i] + si[i] * si[i];
            zacc += (i & mask) ? -pv : pv;
        }
        z[w] = zacc;
    }
#pragma unroll
    for (int c = 0; c < 10; c++) {
        float v = cb[c];
#pragma unroll
        for (int w = 0; w < 4; w++) v = fmaf(cw[c * 4 + w], z[w], v);
        out[(size_t)b * 10 + c] = v;
    }
}

// ---------------------------------------------------------------------------
extern "C" void kernel_launch(void* const* d_in, const int* in_sizes, int n_in,
                              void* d_out, int out_size, void* d_ws, size_t ws_size,
                              hipStream_t stream) {
    const float* x   = (const float*)d_in[0];
    const float* c1w = (const float*)d_in[1];
    const float* c1b = (const float*)d_in[2];
    const float* c2w = (const float*)d_in[3];
    const float* c2b = (const float*)d_in[4];
    const float* f1w = (const float*)d_in[5];
    const float* f1b = (const float*)d_in[6];
    const float* f2w = (const float*)d_in[7];
    const float* f2b = (const float*)d_in[8];
    const float* qw  = (const float*)d_in[9];
    const float* cw  = (const float*)d_in[10];
    const float* cb  = (const float*)d_in[11];
    float* out = (float*)d_out;

    float* ws2 = (float*)d_ws;                   // B*256 fp32 (h2)
    float* ws3 = ws2 + (size_t)BATCH_N * 256;    // B*4   fp32 (angles)

    k12_conv<<<BATCH_N / 2, 128, 0, stream>>>(x, c1w, c1b, c2w, c2b, ws2);
    k3_fc<<<BATCH_N / 64, 256, 0, stream>>>(ws2, f1w, f1b, f2w, f2b, ws3);
    k4_circuit<<<BATCH_N / 256, 256, 0, stream>>>(ws3, qw, cw, cb, out);
}

// Round 3
// 321.060 us; speedup vs baseline: 1.2720x; 1.2720x over previous
//
#include <hip/hip_runtime.h>
#include <math.h>

#define BATCH_N 16384

// ---------------------------------------------------------------------------
// K1: conv1 (1->6,5x5) + relu + pool -> h1 (B,6,12,12)
// Block = 8 samples, 256 threads. Task = (sample, 2x2 pooled quad): 8x8 patch
// in registers serves 4x4 conv positions for all 6 oc (two 3-oc passes).
// Weights/bias staged in LDS (uniform-address broadcast reads). Output staged
// in LDS then stored as coalesced float4.
// ---------------------------------------------------------------------------
__global__ __launch_bounds__(256) void k1_conv1(const float* __restrict__ x,
                                                const float* __restrict__ w1,
                                                const float* __restrict__ b1,
                                                float* __restrict__ h1) {
    __shared__ float xs[8 * 784];
    __shared__ float hs[8 * 864];
    __shared__ float ws[160];  // 150 weights + 6 bias
    const int tid = threadIdx.x;
    const int b0 = blockIdx.x * 8;

    for (int i = tid; i < 1568; i += 256)
        ((float4*)xs)[i] = ((const float4*)(x + (size_t)b0 * 784))[i];
    if (tid < 150) ws[tid] = w1[tid];
    if (tid < 6) ws[150 + tid] = b1[tid];
    __syncthreads();

    // 8 samples x 36 quads = 288 tasks
    for (int t = tid; t < 288; t += 256) {
        const int s = t / 36;
        const int q = t - s * 36;
        const int qy = q / 6, qx = q - (q / 6) * 6;
        const float* xp = xs + s * 784 + (4 * qy) * 28 + 4 * qx;
        float p[8][8];
#pragma unroll
        for (int r = 0; r < 8; r++) {
            float4 u = *(const float4*)(xp + r * 28);
            float4 v = *(const float4*)(xp + r * 28 + 4);
            p[r][0] = u.x; p[r][1] = u.y; p[r][2] = u.z; p[r][3] = u.w;
            p[r][4] = v.x; p[r][5] = v.y; p[r][6] = v.z; p[r][7] = v.w;
        }
#pragma unroll
        for (int pass = 0; pass < 2; pass++) {
            float acc[3][4][4];
#pragma unroll
            for (int o = 0; o < 3; o++) {
                const float bv = ws[150 + pass * 3 + o];
#pragma unroll
                for (int dy = 0; dy < 4; dy++)
#pragma unroll
                    for (int dx = 0; dx < 4; dx++) acc[o][dy][dx] = bv;
            }
#pragma unroll
            for (int ky = 0; ky < 5; ky++)
#pragma unroll
                for (int kx = 0; kx < 5; kx++) {
#pragma unroll
                    for (int o = 0; o < 3; o++) {
                        const float wv = ws[(pass * 3 + o) * 25 + ky * 5 + kx];
#pragma unroll
                        for (int dy = 0; dy < 4; dy++)
#pragma unroll
                            for (int dx = 0; dx < 4; dx++)
                                acc[o][dy][dx] = fmaf(wv, p[ky + dy][kx + dx], acc[o][dy][dx]);
                    }
                }
#pragma unroll
            for (int o = 0; o < 3; o++)
#pragma unroll
                for (int i = 0; i < 2; i++)
#pragma unroll
                    for (int j = 0; j < 2; j++) {
                        const float m = fmaxf(fmaxf(acc[o][2 * i][2 * j],     acc[o][2 * i][2 * j + 1]),
                                              fmaxf(acc[o][2 * i + 1][2 * j], acc[o][2 * i + 1][2 * j + 1]));
                        hs[s * 864 + (pass * 3 + o) * 144 + (2 * qy + i) * 12 + (2 * qx + j)] =
                            fmaxf(m, 0.f);
                    }
        }
    }
    __syncthreads();

    for (int i = tid; i < 1728; i += 256)
        ((float4*)(h1 + (size_t)b0 * 864))[i] = ((const float4*)hs)[i];
}

// ---------------------------------------------------------------------------
// K2: conv2 (6->16,5x5) + relu + pool -> h2 (B,256)
// Block = 4 samples, 256 threads (wave = sample). Thread = (oc, 2x2 pooled
// quad): 8x8 register patch per ic serves 16 conv positions for its oc.
// Weights in LDS: addr (oc*6+ic)*25+k -> oc*150 mod 32 hits 16 distinct banks.
// ---------------------------------------------------------------------------
__global__ __launch_bounds__(256) void k2_conv2(const float* __restrict__ h1,
                                                const float* __restrict__ w2,
                                                const float* __restrict__ b2,
                                                float* __restrict__ h2out) {
    __shared__ float hs[4 * 864];
    __shared__ float ws[2400];
    __shared__ float bs[16];
    __shared__ float stage[4 * 256];
    const int tid = threadIdx.x;
    const int b0 = blockIdx.x * 4;

    for (int i = tid; i < 864; i += 256)
        ((float4*)hs)[i] = ((const float4*)(h1 + (size_t)b0 * 864))[i];
    for (int i = tid; i < 2400; i += 256) ws[i] = w2[i];
    if (tid < 16) bs[tid] = b2[tid];
    __syncthreads();

    const int s = tid >> 6;           // sample within block (one wave each)
    const int lane = tid & 63;
    const int oc = lane & 15;
    const int quad = lane >> 4;       // 0..3
    const int qy = quad >> 1, qx = quad & 1;

    float acc[4][4];
    {
        const float bv = bs[oc];
#pragma unroll
        for (int dy = 0; dy < 4; dy++)
#pragma unroll
            for (int dx = 0; dx < 4; dx++) acc[dy][dx] = bv;
    }

    for (int ic = 0; ic < 6; ic++) {
        const float* xp = hs + s * 864 + ic * 144 + (4 * qy) * 12 + 4 * qx;
        float p[8][8];
#pragma unroll
        for (int r = 0; r < 8; r++) {
            float4 u = *(const float4*)(xp + r * 12);
            float4 v = *(const float4*)(xp + r * 12 + 4);
            p[r][0] = u.x; p[r][1] = u.y; p[r][2] = u.z; p[r][3] = u.w;
            p[r][4] = v.x; p[r][5] = v.y; p[r][6] = v.z; p[r][7] = v.w;
        }
        const float* wp = ws + (oc * 6 + ic) * 25;
#pragma unroll
        for (int ky = 0; ky < 5; ky++)
#pragma unroll
            for (int kx = 0; kx < 5; kx++) {
                const float wv = wp[ky * 5 + kx];
#pragma unroll
                for (int dy = 0; dy < 4; dy++)
#pragma unroll
                    for (int dx = 0; dx < 4; dx++)
                        acc[dy][dx] = fmaf(wv, p[ky + dy][kx + dx], acc[dy][dx]);
            }
    }

#pragma unroll
    for (int i = 0; i < 2; i++)
#pragma unroll
        for (int j = 0; j < 2; j++) {
            const float m = fmaxf(fmaxf(acc[2 * i][2 * j],     acc[2 * i][2 * j + 1]),
                                  fmaxf(acc[2 * i + 1][2 * j], acc[2 * i + 1][2 * j + 1]));
            stage[s * 256 + oc * 16 + (2 * qy + i) * 4 + (2 * qx + j)] = fmaxf(m, 0.f);
        }
    __syncthreads();

    ((float4*)(h2out + (size_t)b0 * 256))[tid] = ((const float4*)stage)[tid];
}

// ---------------------------------------------------------------------------
// K3: fc1 (256->120)+relu, fc2 (120->4), pi*sigmoid -> angles (B,4)
// Tile 32 samples x 128 outs, 256 threads = 16x16, thread = 2x8 micro-tile,
// k-pairs via float2 LDS reads. Grid 512 -> 2 blocks/CU (fixes round-1/2's
// 1-block/CU occupancy hole).
// ---------------------------------------------------------------------------
__global__ __launch_bounds__(256) void k3_fc(const float* __restrict__ h2,
                                             const float* __restrict__ w1,
                                             const float* __restrict__ b1,
                                             const float* __restrict__ w2,
                                             const float* __restrict__ b2,
                                             float* __restrict__ angles) {
    __shared__ float As[32 * 18];
    __shared__ float Bs[128 * 18];
    __shared__ float Hs[32 * 121];
    const int tid = threadIdx.x;
    const int s0 = blockIdx.x * 32;
    const int tx = tid & 15, ty = tid >> 4;

    float acc[2][8];
#pragma unroll
    for (int i = 0; i < 2; i++)
#pragma unroll
        for (int j = 0; j < 8; j++) acc[i][j] = 0.f;

    for (int k0 = 0; k0 < 256; k0 += 16) {
#pragma unroll
        for (int i = 0; i < 2; i++)
            As[(ty + 16 * i) * 18 + tx] = h2[(size_t)(s0 + ty + 16 * i) * 256 + k0 + tx];
#pragma unroll
        for (int j = 0; j < 8; j++) {
            const int n = ty + 16 * j;
            Bs[n * 18 + tx] = (n < 120) ? w1[(size_t)n * 256 + k0 + tx] : 0.f;
        }
        __syncthreads();
#pragma unroll
        for (int kk = 0; kk < 16; kk += 2) {
            float2 av[2], bv[8];
#pragma unroll
            for (int i = 0; i < 2; i++)
                av[i] = *(const float2*)&As[(ty + 16 * i) * 18 + kk];
#pragma unroll
            for (int j = 0; j < 8; j++)
                bv[j] = *(const float2*)&Bs[(tx + 16 * j) * 18 + kk];
#pragma unroll
            for (int i = 0; i < 2; i++)
#pragma unroll
                for (int j = 0; j < 8; j++) {
                    acc[i][j] = fmaf(av[i].x, bv[j].x, acc[i][j]);
                    acc[i][j] = fmaf(av[i].y, bv[j].y, acc[i][j]);
                }
        }
        __syncthreads();
    }

#pragma unroll
    for (int j = 0; j < 8; j++) {
        const int n = tx + 16 * j;
        if (n < 120) {
            const float bv = b1[n];
#pragma unroll
            for (int i = 0; i < 2; i++)
                Hs[(ty + 16 * i) * 121 + n] = fmaxf(acc[i][j] + bv, 0.f);
        }
    }
    __syncthreads();

    if (tid < 128) {
        const int s = tid >> 2, m = tid & 3;
        float f = b2[m];
        for (int n = 0; n < 120; n++) f = fmaf(w2[m * 120 + n], Hs[s * 121 + n], f);
        const float ang = 3.14159265358979323846f / (1.f + expf(-f));
        angles[(size_t)(s0 + s) * 4 + m] = ang;
    }
}

// ---------------------------------------------------------------------------
// K4: 4-qubit, 3-layer circuit + classifier (4->10). One thread per sample.
// ---------------------------------------------------------------------------
__global__ __launch_bounds__(256) void k4_circuit(const float* __restrict__ angles,
                                                  const float* __restrict__ qw,
                                                  const float* __restrict__ cw,
                                                  const float* __restrict__ cb,
                                                  float* __restrict__ out) {
    const int b = blockIdx.x * 256 + threadIdx.x;
    const float4 a4 = ((const float4*)angles)[b];
    const float av[4] = {a4.x, a4.y, a4.z, a4.w};

    float sr[16], si[16];
#pragma unroll
    for (int i = 0; i < 16; i++) { sr[i] = 0.f; si[i] = 0.f; }
    sr[0] = 1.f;

#pragma unroll
    for (int l = 0; l < 3; l++) {
#pragma unroll
        for (int w = 0; w < 4; w++) {
            const float phi = qw[(l * 4 + w) * 3 + 0];
            const float th  = qw[(l * 4 + w) * 3 + 1];
            const float om  = qw[(l * 4 + w) * 3 + 2];
            const float ct = cosf(0.5f * th), st = sinf(0.5f * th);
            const float ap = 0.5f * (phi + om), bm = 0.5f * (phi - om);
            const float ca = cosf(ap), sa = sinf(ap);
            const float cbm = cosf(bm), sbm = sinf(bm);
            const float m00r =  ct * ca,  m00i = -ct * sa;
            const float m01r = -st * cbm, m01i = -st * sbm;
            const float m10r =  st * cbm, m10i = -st * sbm;
            const float m11r =  ct * ca,  m11i =  ct * sa;
            const int mask = 8 >> w;
#pragma unroll
            for (int i = 0; i < 16; i++)
                if (!(i & mask)) {
                    const int j = i | mask;
                    const float xr = sr[i], xi = si[i], yr = sr[j], yi = si[j];
                    sr[i] = m00r * xr - m00i * xi + m01r * yr - m01i * yi;
                    si[i] = m00r * xi + m00i * xr + m01r * yi + m01i * yr;
                    sr[j] = m10r * xr - m10i * xi + m11r * yr - m11i * yi;
                    si[j] = m10r * xi + m10i * xr + m11r * yi + m11i * yr;
                }
        }
#pragma unroll
        for (int w = 0; w < 4; w++) {
            const int mc = 8 >> w, mt = 8 >> ((w + 1) & 3);
#pragma unroll
            for (int i = 0; i < 16; i++)
                if ((i & mc) && !(i & mt)) {
                    const int j = i | mt;
                    const float tr = sr[i], ti = si[i];
                    sr[i] = sr[j]; si[i] = si[j];
                    sr[j] = tr;    si[j] = ti;
                }
        }
#pragma unroll
        for (int w = 0; w < 4; w++) {
            const float c = cosf(0.5f * av[w]), s = sinf(0.5f * av[w]);
            const int mask = 8 >> w;
#pragma unroll
            for (int i = 0; i < 16; i++)
                if (!(i & mask)) {
                    const int j = i | mask;
                    const float xr = sr[i], xi = si[i], yr = sr[j], yi = si[j];
                    sr[i] = c * xr + s * yi;
                    si[i] = c * xi - s * yr;
                    sr[j] = c * yr + s * xi;
                    si[j] = c * yi - s * xr;
                }
        }
    }

    float z[4];
#pragma unroll
    for (int w = 0; w < 4; w++) {
        const int mask = 8 >> w;
        float zacc = 0.f;
#pragma unroll
        for (int i = 0; i < 16; i++) {
            const float pv = sr[i] * sr[i] + si[i] * si[i];
            zacc += (i & mask) ? -pv : pv;
        }
        z[w] = zacc;
    }
#pragma unroll
    for (int c = 0; c < 10; c++) {
        float v = cb[c];
#pragma unroll
        for (int w = 0; w < 4; w++) v = fmaf(cw[c * 4 + w], z[w], v);
        out[(size_t)b * 10 + c] = v;
    }
}

// ---------------------------------------------------------------------------
extern "C" void kernel_launch(void* const* d_in, const int* in_sizes, int n_in,
                              void* d_out, int out_size, void* d_ws, size_t ws_size,
                              hipStream_t stream) {
    const float* x   = (const float*)d_in[0];
    const float* c1w = (const float*)d_in[1];
    const float* c1b = (const float*)d_in[2];
    const float* c2w = (const float*)d_in[3];
    const float* c2b = (const float*)d_in[4];
    const float* f1w = (const float*)d_in[5];
    const float* f1b = (const float*)d_in[6];
    const float* f2w = (const float*)d_in[7];
    const float* f2b = (const float*)d_in[8];
    const float* qw  = (const float*)d_in[9];
    const float* cw  = (const float*)d_in[10];
    const float* cb  = (const float*)d_in[11];
    float* out = (float*)d_out;

    float* ws1 = (float*)d_ws;                    // B*864 (h1)
    float* ws2 = ws1 + (size_t)BATCH_N * 864;     // B*256 (h2)
    float* ws3 = ws2 + (size_t)BATCH_N * 256;     // B*4   (angles)

    k1_conv1<<<BATCH_N / 8, 256, 0, stream>>>(x, c1w, c1b, ws1);
    k2_conv2<<<BATCH_N / 4, 256, 0, stream>>>(ws1, c2w, c2b, ws2);
    k3_fc<<<BATCH_N / 32, 256, 0, stream>>>(ws2, f1w, f1b, f2w, f2b, ws3);
    k4_circuit<<<BATCH_N / 256, 256, 0, stream>>>(ws3, qw, cw, cb, out);
}

// Round 4
// 259.783 us; speedup vs baseline: 1.5720x; 1.2359x over previous
//
#include <hip/hip_runtime.h>
#include <math.h>

#define BATCH_N 16384

// ---------------------------------------------------------------------------
// K1: conv1 (1->6,5x5) + relu + pool -> h1 (B,6,12,12)
// Block = 8 samples, 256 threads, LDS = input only (~26 KB; no output staging
// -- direct stores are wave-coalesced). Task = (sample, pooled pos): 6x6
// patch (18 ds_read_b64) serves 4 conv positions x ALL 6 oc (600 FMA).
// Weights transposed in LDS (wt[k*8+oc]) so each tap is b128+b64 broadcast.
// ---------------------------------------------------------------------------
__global__ __launch_bounds__(256) void k1_conv1(const float* __restrict__ x,
                                                const float* __restrict__ w1,
                                                const float* __restrict__ b1,
                                                float* __restrict__ h1) {
    __shared__ float xs[8 * 784];
    __shared__ float wt[25 * 8];   // [tap][oc], padded to 8
    __shared__ float bs[8];
    const int tid = threadIdx.x;
    const int b0 = blockIdx.x * 8;

    for (int i = tid; i < 1568; i += 256)
        ((float4*)xs)[i] = ((const float4*)(x + (size_t)b0 * 784))[i];
    if (tid < 200) wt[tid] = 0.f;
    __syncthreads();  // cheap way to avoid write-order races on wt pad
    if (tid < 150) wt[(tid % 25) * 8 + tid / 25] = w1[tid];
    if (tid < 6) bs[tid] = b1[tid];
    __syncthreads();

    for (int t = tid; t < 1152; t += 256) {
        const int s = t / 144;
        const int r = t - s * 144;
        const int py = r / 12, px = r - (r / 12) * 12;
        const float* xp = xs + s * 784 + (2 * py) * 28 + 2 * px;

        float p[6][6];
#pragma unroll
        for (int rr = 0; rr < 6; rr++) {
            float2 u = *(const float2*)(xp + rr * 28);
            float2 v = *(const float2*)(xp + rr * 28 + 2);
            float2 w = *(const float2*)(xp + rr * 28 + 4);
            p[rr][0] = u.x; p[rr][1] = u.y; p[rr][2] = v.x;
            p[rr][3] = v.y; p[rr][4] = w.x; p[rr][5] = w.y;
        }

        float acc[6][4];
#pragma unroll
        for (int o = 0; o < 6; o++) {
            const float bv = bs[o];
            acc[o][0] = bv; acc[o][1] = bv; acc[o][2] = bv; acc[o][3] = bv;
        }

#pragma unroll
        for (int ky = 0; ky < 5; ky++)
#pragma unroll
            for (int kx = 0; kx < 5; kx++) {
                const int k = ky * 5 + kx;
                const float4 wA = *(const float4*)&wt[k * 8];      // oc 0..3
                const float2 wB = *(const float2*)&wt[k * 8 + 4];  // oc 4..5
                const float p00 = p[ky][kx],     p01 = p[ky][kx + 1];
                const float p10 = p[ky + 1][kx], p11 = p[ky + 1][kx + 1];
                acc[0][0] = fmaf(wA.x, p00, acc[0][0]); acc[0][1] = fmaf(wA.x, p01, acc[0][1]);
                acc[0][2] = fmaf(wA.x, p10, acc[0][2]); acc[0][3] = fmaf(wA.x, p11, acc[0][3]);
                acc[1][0] = fmaf(wA.y, p00, acc[1][0]); acc[1][1] = fmaf(wA.y, p01, acc[1][1]);
                acc[1][2] = fmaf(wA.y, p10, acc[1][2]); acc[1][3] = fmaf(wA.y, p11, acc[1][3]);
                acc[2][0] = fmaf(wA.z, p00, acc[2][0]); acc[2][1] = fmaf(wA.z, p01, acc[2][1]);
                acc[2][2] = fmaf(wA.z, p10, acc[2][2]); acc[2][3] = fmaf(wA.z, p11, acc[2][3]);
                acc[3][0] = fmaf(wA.w, p00, acc[3][0]); acc[3][1] = fmaf(wA.w, p01, acc[3][1]);
                acc[3][2] = fmaf(wA.w, p10, acc[3][2]); acc[3][3] = fmaf(wA.w, p11, acc[3][3]);
                acc[4][0] = fmaf(wB.x, p00, acc[4][0]); acc[4][1] = fmaf(wB.x, p01, acc[4][1]);
                acc[4][2] = fmaf(wB.x, p10, acc[4][2]); acc[4][3] = fmaf(wB.x, p11, acc[4][3]);
                acc[5][0] = fmaf(wB.y, p00, acc[5][0]); acc[5][1] = fmaf(wB.y, p01, acc[5][1]);
                acc[5][2] = fmaf(wB.y, p10, acc[5][2]); acc[5][3] = fmaf(wB.y, p11, acc[5][3]);
            }

        float* op = h1 + (size_t)(b0 + s) * 864 + py * 12 + px;
#pragma unroll
        for (int o = 0; o < 6; o++) {
            const float m = fmaxf(fmaxf(acc[o][0], acc[o][1]), fmaxf(acc[o][2], acc[o][3]));
            op[o * 144] = fmaxf(m, 0.f);
        }
    }
}

// ---------------------------------------------------------------------------
// K2: conv2 (6->16,5x5) + relu + pool -> h2 (B,256)   [unchanged from R3]
// ---------------------------------------------------------------------------
__global__ __launch_bounds__(256) void k2_conv2(const float* __restrict__ h1,
                                                const float* __restrict__ w2,
                                                const float* __restrict__ b2,
                                                float* __restrict__ h2out) {
    __shared__ float hs[4 * 864];
    __shared__ float ws[2400];
    __shared__ float bs[16];
    __shared__ float stage[4 * 256];
    const int tid = threadIdx.x;
    const int b0 = blockIdx.x * 4;

    for (int i = tid; i < 864; i += 256)
        ((float4*)hs)[i] = ((const float4*)(h1 + (size_t)b0 * 864))[i];
    for (int i = tid; i < 2400; i += 256) ws[i] = w2[i];
    if (tid < 16) bs[tid] = b2[tid];
    __syncthreads();

    const int s = tid >> 6;
    const int lane = tid & 63;
    const int oc = lane & 15;
    const int quad = lane >> 4;
    const int qy = quad >> 1, qx = quad & 1;

    float acc[4][4];
    {
        const float bv = bs[oc];
#pragma unroll
        for (int dy = 0; dy < 4; dy++)
#pragma unroll
            for (int dx = 0; dx < 4; dx++) acc[dy][dx] = bv;
    }

    for (int ic = 0; ic < 6; ic++) {
        const float* xp = hs + s * 864 + ic * 144 + (4 * qy) * 12 + 4 * qx;
        float p[8][8];
#pragma unroll
        for (int r = 0; r < 8; r++) {
            float4 u = *(const float4*)(xp + r * 12);
            float4 v = *(const float4*)(xp + r * 12 + 4);
            p[r][0] = u.x; p[r][1] = u.y; p[r][2] = u.z; p[r][3] = u.w;
            p[r][4] = v.x; p[r][5] = v.y; p[r][6] = v.z; p[r][7] = v.w;
        }
        const float* wp = ws + (oc * 6 + ic) * 25;
#pragma unroll
        for (int ky = 0; ky < 5; ky++)
#pragma unroll
            for (int kx = 0; kx < 5; kx++) {
                const float wv = wp[ky * 5 + kx];
#pragma unroll
                for (int dy = 0; dy < 4; dy++)
#pragma unroll
                    for (int dx = 0; dx < 4; dx++)
                        acc[dy][dx] = fmaf(wv, p[ky + dy][kx + dx], acc[dy][dx]);
            }
    }

#pragma unroll
    for (int i = 0; i < 2; i++)
#pragma unroll
        for (int j = 0; j < 2; j++) {
            const float m = fmaxf(fmaxf(acc[2 * i][2 * j],     acc[2 * i][2 * j + 1]),
                                  fmaxf(acc[2 * i + 1][2 * j], acc[2 * i + 1][2 * j + 1]));
            stage[s * 256 + oc * 16 + (2 * qy + i) * 4 + (2 * qx + j)] = fmaxf(m, 0.f);
        }
    __syncthreads();

    ((float4*)(h2out + (size_t)b0 * 256))[tid] = ((const float4*)stage)[tid];
}

// ---------------------------------------------------------------------------
// K3: fc1 (256->120)+relu, fc2 (120->4), pi*sigmoid -> angles  [unchanged]
// ---------------------------------------------------------------------------
__global__ __launch_bounds__(256) void k3_fc(const float* __restrict__ h2,
                                             const float* __restrict__ w1,
                                             const float* __restrict__ b1,
                                             const float* __restrict__ w2,
                                             const float* __restrict__ b2,
                                             float* __restrict__ angles) {
    __shared__ float As[32 * 18];
    __shared__ float Bs[128 * 18];
    __shared__ float Hs[32 * 121];
    const int tid = threadIdx.x;
    const int s0 = blockIdx.x * 32;
    const int tx = tid & 15, ty = tid >> 4;

    float acc[2][8];
#pragma unroll
    for (int i = 0; i < 2; i++)
#pragma unroll
        for (int j = 0; j < 8; j++) acc[i][j] = 0.f;

    for (int k0 = 0; k0 < 256; k0 += 16) {
#pragma unroll
        for (int i = 0; i < 2; i++)
            As[(ty + 16 * i) * 18 + tx] = h2[(size_t)(s0 + ty + 16 * i) * 256 + k0 + tx];
#pragma unroll
        for (int j = 0; j < 8; j++) {
            const int n = ty + 16 * j;
            Bs[n * 18 + tx] = (n < 120) ? w1[(size_t)n * 256 + k0 + tx] : 0.f;
        }
        __syncthreads();
#pragma unroll
        for (int kk = 0; kk < 16; kk += 2) {
            float2 av[2], bv[8];
#pragma unroll
            for (int i = 0; i < 2; i++)
                av[i] = *(const float2*)&As[(ty + 16 * i) * 18 + kk];
#pragma unroll
            for (int j = 0; j < 8; j++)
                bv[j] = *(const float2*)&Bs[(tx + 16 * j) * 18 + kk];
#pragma unroll
            for (int i = 0; i < 2; i++)
#pragma unroll
                for (int j = 0; j < 8; j++) {
                    acc[i][j] = fmaf(av[i].x, bv[j].x, acc[i][j]);
                    acc[i][j] = fmaf(av[i].y, bv[j].y, acc[i][j]);
                }
        }
        __syncthreads();
    }

#pragma unroll
    for (int j = 0; j < 8; j++) {
        const int n = tx + 16 * j;
        if (n < 120) {
            const float bv = b1[n];
#pragma unroll
            for (int i = 0; i < 2; i++)
                Hs[(ty + 16 * i) * 121 + n] = fmaxf(acc[i][j] + bv, 0.f);
        }
    }
    __syncthreads();

    if (tid < 128) {
        const int s = tid >> 2, m = tid & 3;
        float f = b2[m];
        for (int n = 0; n < 120; n++) f = fmaf(w2[m * 120 + n], Hs[s * 121 + n], f);
        const float ang = 3.14159265358979323846f / (1.f + expf(-f));
        angles[(size_t)(s0 + s) * 4 + m] = ang;
    }
}

// ---------------------------------------------------------------------------
// K4: 4-qubit, 3-layer circuit + classifier (4->10). One thread per sample.
// ---------------------------------------------------------------------------
__global__ __launch_bounds__(256) void k4_circuit(const float* __restrict__ angles,
                                                  const float* __restrict__ qw,
                                                  const float* __restrict__ cw,
                                                  const float* __restrict__ cb,
                                                  float* __restrict__ out) {
    const int b = blockIdx.x * 256 + threadIdx.x;
    const float4 a4 = ((const float4*)angles)[b];
    const float av[4] = {a4.x, a4.y, a4.z, a4.w};

    float sr[16], si[16];
#pragma unroll
    for (int i = 0; i < 16; i++) { sr[i] = 0.f; si[i] = 0.f; }
    sr[0] = 1.f;

#pragma unroll
    for (int l = 0; l < 3; l++) {
#pragma unroll
        for (int w = 0; w < 4; w++) {
            const float phi = qw[(l * 4 + w) * 3 + 0];
            const float th  = qw[(l * 4 + w) * 3 + 1];
            const float om  = qw[(l * 4 + w) * 3 + 2];
            const float ct = cosf(0.5f * th), st = sinf(0.5f * th);
            const float ap = 0.5f * (phi + om), bm = 0.5f * (phi - om);
            const float ca = cosf(ap), sa = sinf(ap);
            const float cbm = cosf(bm), sbm = sinf(bm);
            const float m00r =  ct * ca,  m00i = -ct * sa;
            const float m01r = -st * cbm, m01i = -st * sbm;
            const float m10r =  st * cbm, m10i = -st * sbm;
            const float m11r =  ct * ca,  m11i =  ct * sa;
            const int mask = 8 >> w;
#pragma unroll
            for (int i = 0; i < 16; i++)
                if (!(i & mask)) {
                    const int j = i | mask;
                    const float xr = sr[i], xi = si[i], yr = sr[j], yi = si[j];
                    sr[i] = m00r * xr - m00i * xi + m01r * yr - m01i * yi;
                    si[i] = m00r * xi + m00i * xr + m01r * yi + m01i * yr;
                    sr[j] = m10r * xr - m10i * xi + m11r * yr - m11i * yi;
                    si[j] = m10r * xi + m10i * xr + m11r * yi + m11i * yr;
                }
        }
#pragma unroll
        for (int w = 0; w < 4; w++) {
            const int mc = 8 >> w, mt = 8 >> ((w + 1) & 3);
#pragma unroll
            for (int i = 0; i < 16; i++)
                if ((i & mc) && !(i & mt)) {
                    const int j = i | mt;
                    const float tr = sr[i], ti = si[i];
                    sr[i] = sr[j]; si[i] = si[j];
                    sr[j] = tr;    si[j] = ti;
                }
        }
#pragma unroll
        for (int w = 0; w < 4; w++) {
            const float c = cosf(0.5f * av[w]), s = sinf(0.5f * av[w]);
            const int mask = 8 >> w;
#pragma unroll
            for (int i = 0; i < 16; i++)
                if (!(i & mask)) {
                    const int j = i | mask;
                    const float xr = sr[i], xi = si[i], yr = sr[j], yi = si[j];
                    sr[i] = c * xr + s * yi;
                    si[i] = c * xi - s * yr;
                    sr[j] = c * yr + s * xi;
                    si[j] = c * yi - s * xr;
                }
        }
    }

    float z[4];
#pragma unroll
    for (int w = 0; w < 4; w++) {
        const int mask = 8 >> w;
        float zacc = 0.f;
#pragma unroll
        for (int i = 0; i < 16; i++) {
            const float pv = sr[i] * sr[i] + si[i] * si[i];
            zacc += (i & mask) ? -pv : pv;
        }
        z[w] = zacc;
    }
#pragma unroll
    for (int c = 0; c < 10; c++) {
        float v = cb[c];
#pragma unroll
        for (int w = 0; w < 4; w++) v = fmaf(cw[c * 4 + w], z[w], v);
        out[(size_t)b * 10 + c] = v;
    }
}

// ---------------------------------------------------------------------------
extern "C" void kernel_launch(void* const* d_in, const int* in_sizes, int n_in,
                              void* d_out, int out_size, void* d_ws, size_t ws_size,
                              hipStream_t stream) {
    const float* x   = (const float*)d_in[0];
    const float* c1w = (const float*)d_in[1];
    const float* c1b = (const float*)d_in[2];
    const float* c2w = (const float*)d_in[3];
    const float* c2b = (const float*)d_in[4];
    const float* f1w = (const float*)d_in[5];
    const float* f1b = (const float*)d_in[6];
    const float* f2w = (const float*)d_in[7];
    const float* f2b = (const float*)d_in[8];
    const float* qw  = (const float*)d_in[9];
    const float* cw  = (const float*)d_in[10];
    const float* cb  = (const float*)d_in[11];
    float* out = (float*)d_out;

    float* ws1 = (float*)d_ws;                    // B*864 (h1)
    float* ws2 = ws1 + (size_t)BATCH_N * 864;     // B*256 (h2)
    float* ws3 = ws2 + (size_t)BATCH_N * 256;     // B*4   (angles)

    k1_conv1<<<BATCH_N / 8, 256, 0, stream>>>(x, c1w, c1b, ws1);
    k2_conv2<<<BATCH_N / 4, 256, 0, stream>>>(ws1, c2w, c2b, ws2);
    k3_fc<<<BATCH_N / 32, 256, 0, stream>>>(ws2, f1w, f1b, f2w, f2b, ws3);
    k4_circuit<<<BATCH_N / 256, 256, 0, stream>>>(ws3, qw, cw, cb, out);
}